// Round 1
// baseline (495.424 us; speedup 1.0000x reference)
//
#include <hip/hip_runtime.h>
#include <hip/hip_bf16.h>

#define HIDDEN 128
#define MIX 8

__device__ __forceinline__ float gelu_exact(float x) {
    // exact gelu: x * 0.5 * (1 + erf(x / sqrt(2)))
    return 0.5f * x * (1.0f + erff(x * 0.7071067811865476f));
}

// K1: per-node hyper-net weights.
// Wnode[n][m] = sum_k gelu( X[n] . W_A[j] )[j=k] * W_B[m][k]
// One block (128 threads) per node.
__global__ __launch_bounds__(128) void k_wnode(const float* __restrict__ X,
                                               const float* __restrict__ W_A,
                                               const float* __restrict__ W_B,
                                               float* __restrict__ Wnode) {
    int n = blockIdx.x;
    int t = threadIdx.x;
    __shared__ float xs[HIDDEN];
    __shared__ float gs[HIDDEN];
    xs[t] = X[(size_t)n * HIDDEN + t];
    __syncthreads();
    const float* wa = W_A + (size_t)t * HIDDEN;
    float acc = 0.f;
#pragma unroll 8
    for (int k = 0; k < HIDDEN; ++k) acc += xs[k] * wa[k];
    gs[t] = gelu_exact(acc);
    __syncthreads();
    if (t < MIX) {
        const float* wb = W_B + (size_t)t * HIDDEN;
        float a = 0.f;
#pragma unroll 8
        for (int k = 0; k < HIDDEN; ++k) a += gs[k] * wb[k];
        Wnode[n * MIX + t] = a;
    }
}

// K2: histogram of dst + echo src/dst as float outputs.
__global__ __launch_bounds__(256) void k_hist(const int* __restrict__ src,
                                              const int* __restrict__ dst,
                                              int* __restrict__ counts,
                                              float* __restrict__ out_src,
                                              float* __restrict__ out_dst,
                                              int E) {
    int e = blockIdx.x * 256 + threadIdx.x;
    if (e < E) {
        int d = dst[e];
        atomicAdd(&counts[d], 1);
        out_src[e] = (float)src[e];
        out_dst[e] = (float)d;
    }
}

// K3: exclusive prefix sum over counts -> offsets (single block, 256 threads).
__global__ __launch_bounds__(256) void k_scan(const int* __restrict__ counts,
                                              int* __restrict__ offsets,
                                              int N) {
    __shared__ int ls[256];
    int t = threadIdx.x;
    int chunk = (N + 255) / 256;
    int begin = t * chunk;
    int end = begin + chunk; if (end > N) end = N;
    int s = 0;
    for (int i = begin; i < end && i >= 0; ++i) s += counts[i];
    ls[t] = s;
    __syncthreads();
    // Hillis-Steele inclusive scan
    for (int off = 1; off < 256; off <<= 1) {
        int v = (t >= off) ? ls[t - off] : 0;
        __syncthreads();
        ls[t] += v;
        __syncthreads();
    }
    int run = (t == 0) ? 0 : ls[t - 1];
    for (int i = begin; i < end; ++i) { offsets[i] = run; run += counts[i]; }
    if (t == 255) offsets[N] = run;  // == E
}

// K4: fill CSR edge lists (order within a node is arbitrary; fp-add reorder ok).
__global__ __launch_bounds__(256) void k_fill(const int* __restrict__ dst,
                                              int* __restrict__ cursor,
                                              const int* __restrict__ offsets,
                                              int* __restrict__ csr,
                                              int E) {
    int e = blockIdx.x * 256 + threadIdx.x;
    if (e < E) {
        int d = dst[e];
        int p = atomicAdd(&cursor[d], 1);
        csr[offsets[d] + p] = e;
    }
}

// K5: per-node aggregate (in registers), gelu, then per-edge output.
// Block = 256 threads; thread t owns agg entries flat idx 4t..4t+3,
// i.e. h = t>>1, m in [ (t&1)*4 , (t&1)*4+4 ).
__global__ __launch_bounds__(256) void k_node(const float* __restrict__ X,
                                              const float* __restrict__ Wnode,
                                              const int* __restrict__ src,
                                              const int* __restrict__ csr,
                                              const int* __restrict__ offsets,
                                              float* __restrict__ out_edge) {
    int n = blockIdx.x;
    int t = threadIdx.x;
    int beg = offsets[n];
    int cnt = offsets[n + 1] - beg;
    __shared__ float xs[HIDDEN];
    __shared__ float ws[MIX];
    int h = t >> 1;
    int m0 = (t & 1) * 4;
    float ag0 = 0.f, ag1 = 0.f, ag2 = 0.f, ag3 = 0.f;

    for (int i = 0; i < cnt; ++i) {
        int e = csr[beg + i];
        int s = src[e];
        if (t < 32) {
            ((float4*)xs)[t] = ((const float4*)(X + (size_t)s * HIDDEN))[t];
        } else if (t >= 64 && t < 64 + MIX) {
            ws[t - 64] = Wnode[s * MIX + (t - 64)];
        }
        __syncthreads();
        float xh = xs[h];
        ag0 += xh * ws[m0 + 0];
        ag1 += xh * ws[m0 + 1];
        ag2 += xh * ws[m0 + 2];
        ag3 += xh * ws[m0 + 3];
        __syncthreads();
    }

    ag0 = gelu_exact(ag0);
    ag1 = gelu_exact(ag1);
    ag2 = gelu_exact(ag2);
    ag3 = gelu_exact(ag3);

    for (int i = 0; i < cnt; ++i) {
        int e = csr[beg + i];
        int s = src[e];
        if (t < MIX) ws[t] = Wnode[s * MIX + t];
        __syncthreads();
        float p = ag0 * ws[m0 + 0] + ag1 * ws[m0 + 1] + ag2 * ws[m0 + 2] + ag3 * ws[m0 + 3];
        p += __shfl_xor(p, 1);  // combine the two half-rows (same wave, lane pair)
        if ((t & 1) == 0) out_edge[(size_t)e * HIDDEN + h] = p;
        __syncthreads();
    }
}

extern "C" void kernel_launch(void* const* d_in, const int* in_sizes, int n_in,
                              void* d_out, int out_size, void* d_ws, size_t ws_size,
                              hipStream_t stream) {
    const float* X   = (const float*)d_in[0];
    const float* W_A = (const float*)d_in[1];
    const float* W_B = (const float*)d_in[2];
    const int*   ei  = (const int*)d_in[3];
    // d_in[4] = num_nodes scalar (derive N from sizes instead)

    const int N = in_sizes[0] / HIDDEN;
    const int E = in_sizes[3] / 2;
    const int* src = ei;
    const int* dst = ei + E;

    float* out      = (float*)d_out;
    float* out_edge = out;                        // (E, 128)
    float* out_src  = out + (size_t)E * HIDDEN;   // (E,)
    float* out_dst  = out_src + E;                // (E,)

    // workspace layout (all 4-byte types):
    // [counts N][cursor N][offsets N+1][csr E][Wnode N*MIX]
    int* counts  = (int*)d_ws;
    int* cursor  = counts + N;
    int* offsets = cursor + N;
    int* csr     = offsets + (N + 1);
    float* Wnode = (float*)(csr + E);

    hipMemsetAsync(counts, 0, sizeof(int) * (size_t)(2 * N), stream);  // counts + cursor

    k_wnode<<<N, 128, 0, stream>>>(X, W_A, W_B, Wnode);

    int eb = (E + 255) / 256;
    k_hist<<<eb, 256, 0, stream>>>(src, dst, counts, out_src, out_dst, E);
    k_scan<<<1, 256, 0, stream>>>(counts, offsets, N);
    k_fill<<<eb, 256, 0, stream>>>(dst, cursor, offsets, csr, E);
    k_node<<<N, 256, 0, stream>>>(X, Wnode, src, csr, offsets, out_edge);
}

// Round 2
// 300.619 us; speedup vs baseline: 1.6480x; 1.6480x over previous
//
#include <hip/hip_runtime.h>
#include <hip/hip_bf16.h>

#define HIDDEN 128
#define MIX 8
#define NB 16     // nodes per block in k_wnode
#define JT 16     // output columns per tile iteration in k_wnode
#define LDP 132   // padded LDS row stride (132%4==0 keeps float4 aligned; 4*? banks spread)

__device__ __forceinline__ float gelu_exact(float x) {
    // exact gelu: x * 0.5 * (1 + erf(x / sqrt(2)))
    return 0.5f * x * (1.0f + erff(x * 0.7071067811865476f));
}

// K1: per-node hyper-net weights, tiled GEMM style.
// Wnode[n][m] = sum_k gelu( X[n] . W_A[k,:] ) * W_B[m][k]
// Block = 256 threads, NB=16 nodes. W_A read exactly once per block, coalesced.
__global__ __launch_bounds__(256) void k_wnode(const float* __restrict__ X,
                                               const float* __restrict__ W_A,
                                               const float* __restrict__ W_B,
                                               float* __restrict__ Wnode,
                                               int N) {
    __shared__ float xs[NB * LDP];   // X rows
    __shared__ float wa[JT * LDP];   // W_A tile
    __shared__ float gs[NB * LDP];   // gelu(X @ W_A^T)
    __shared__ float wb[MIX * LDP];  // W_B
    int t = threadIdx.x;
    int n0 = blockIdx.x * NB;

    // load 16 X rows (2048 floats) coalesced: 8 floats per thread
    {
        int r = t >> 4;
        int c = (t & 15) * 8;
        int rn = n0 + r; if (rn >= N) rn = N - 1;
        const float* xp = X + (size_t)rn * HIDDEN + c;
        float4 a = ((const float4*)xp)[0];
        float4 b = ((const float4*)xp)[1];
        *((float4*)&xs[r * LDP + c]) = a;
        *((float4*)&xs[r * LDP + c + 4]) = b;
    }
    int n = t & 15;    // node within block
    int jl = t >> 4;   // 0..15, column within tile
    __syncthreads();

    for (int jj = 0; jj < HIDDEN / JT; ++jj) {
        int j0 = jj * JT;
        {   // load W_A rows j0..j0+15, coalesced
            int r = t >> 4;
            int c = (t & 15) * 8;
            const float* wp = W_A + (size_t)(j0 + r) * HIDDEN + c;
            float4 a = ((const float4*)wp)[0];
            float4 b = ((const float4*)wp)[1];
            *((float4*)&wa[r * LDP + c]) = a;
            *((float4*)&wa[r * LDP + c + 4]) = b;
        }
        __syncthreads();
        float acc = 0.f;
#pragma unroll 8
        for (int k = 0; k < HIDDEN; ++k)
            acc += xs[n * LDP + k] * wa[jl * LDP + k];
        gs[n * LDP + (j0 + jl)] = gelu_exact(acc);
        __syncthreads();
    }

    // load W_B (8 x 128) coalesced
    if (t < 128) {
        int r = t >> 4;
        int c = (t & 15) * 8;
        const float* wp = W_B + (size_t)r * HIDDEN + c;
        float4 a = ((const float4*)wp)[0];
        float4 b = ((const float4*)wp)[1];
        *((float4*)&wb[r * LDP + c]) = a;
        *((float4*)&wb[r * LDP + c + 4]) = b;
    }
    __syncthreads();

    if (t < NB * MIX) {
        int nn = t >> 3;
        int m = t & 7;
        float acc = 0.f;
#pragma unroll 8
        for (int k = 0; k < HIDDEN; ++k)
            acc += gs[nn * LDP + k] * wb[m * LDP + k];
        int rn = n0 + nn;
        if (rn < N) Wnode[rn * MIX + m] = acc;
    }
}

// K2: histogram of dst + echo src/dst as float outputs.
__global__ __launch_bounds__(256) void k_hist(const int* __restrict__ src,
                                              const int* __restrict__ dst,
                                              int* __restrict__ counts,
                                              float* __restrict__ out_src,
                                              float* __restrict__ out_dst,
                                              int E) {
    int e = blockIdx.x * 256 + threadIdx.x;
    if (e < E) {
        int d = dst[e];
        atomicAdd(&counts[d], 1);
        out_src[e] = (float)src[e];
        out_dst[e] = (float)d;
    }
}

// K3: exclusive prefix sum over counts -> offsets (single block, 1024 threads).
__global__ __launch_bounds__(1024) void k_scan(const int* __restrict__ counts,
                                               int* __restrict__ offsets,
                                               int N) {
    __shared__ int ls[1024];
    int t = threadIdx.x;
    int chunk = (N + 1023) / 1024;
    int begin = t * chunk;
    int end = begin + chunk; if (end > N) end = N;
    int s = 0;
    for (int i = begin; i < end; ++i) s += counts[i];
    ls[t] = s;
    __syncthreads();
    for (int off = 1; off < 1024; off <<= 1) {
        int v = (t >= off) ? ls[t - off] : 0;
        __syncthreads();
        ls[t] += v;
        __syncthreads();
    }
    int run = (t == 0) ? 0 : ls[t - 1];
    for (int i = begin; i < end; ++i) { offsets[i] = run; run += counts[i]; }
    if (t == 1023) offsets[N] = run;  // == E
}

// K4: fill CSR edge lists (order within a node arbitrary; fp-add reorder ok).
__global__ __launch_bounds__(256) void k_fill(const int* __restrict__ dst,
                                              int* __restrict__ cursor,
                                              const int* __restrict__ offsets,
                                              int* __restrict__ csr,
                                              int E) {
    int e = blockIdx.x * 256 + threadIdx.x;
    if (e < E) {
        int d = dst[e];
        int p = atomicAdd(&cursor[d], 1);
        csr[offsets[d] + p] = e;
    }
}

// K5: per-node aggregate (registers), gelu, per-edge output.
// 128 threads/block; thread t owns hidden row h=t, 8 mix accumulators.
// Batches of 4 edges per barrier region, double-buffered LDS + id prefetch.
__global__ __launch_bounds__(128) void k_node(const float* __restrict__ X,
                                              const float* __restrict__ Wnode,
                                              const int* __restrict__ src,
                                              const int* __restrict__ csr,
                                              const int* __restrict__ offsets,
                                              float* __restrict__ out_edge) {
    int n = blockIdx.x;
    int t = threadIdx.x;
    int beg = offsets[n];
    int cnt = offsets[n + 1] - beg;
    if (cnt == 0) return;

    __shared__ int es[2][4];
    __shared__ int ss[2][4];
    __shared__ float xs[2][4][HIDDEN];
    __shared__ float ws[2][4][MIX];

    float ag[MIX];
#pragma unroll
    for (int m = 0; m < MIX; ++m) ag[m] = 0.f;

    // prefetch ids for batch 0
    if (t < 4 && t < cnt) { int e = csr[beg + t]; es[0][t] = e; ss[0][t] = src[e]; }
    __syncthreads();

    int buf = 0;
    for (int i0 = 0; i0 < cnt; i0 += 4, buf ^= 1) {
        int nb = min(4, cnt - i0);
        // issue loads for this batch
        if (t < nb * 32) {
            int b = t >> 5, lane = t & 31;
            ((float4*)xs[buf][b])[lane] =
                ((const float4*)(X + (size_t)ss[buf][b] * HIDDEN))[lane];
        }
        if (t < nb * MIX) {
            int b = t >> 3, m = t & 7;
            ws[buf][b][m] = Wnode[ss[buf][b] * MIX + m];
        }
        // prefetch next batch ids into the other buffer
        int i1 = i0 + 4;
        if (t < 4 && i1 + t < cnt) {
            int e = csr[beg + i1 + t];
            es[buf ^ 1][t] = e; ss[buf ^ 1][t] = src[e];
        }
        __syncthreads();
#pragma unroll
        for (int b = 0; b < 4; ++b) {
            if (b >= nb) break;
            float xh = xs[buf][b][t];
            float4 w0 = *((const float4*)&ws[buf][b][0]);
            float4 w1 = *((const float4*)&ws[buf][b][4]);
            ag[0] += xh * w0.x; ag[1] += xh * w0.y;
            ag[2] += xh * w0.z; ag[3] += xh * w0.w;
            ag[4] += xh * w1.x; ag[5] += xh * w1.y;
            ag[6] += xh * w1.z; ag[7] += xh * w1.w;
        }
    }
    __syncthreads();  // last compute read ws[buf_last]; phase 2 rewrites ws

#pragma unroll
    for (int m = 0; m < MIX; ++m) ag[m] = gelu_exact(ag[m]);

    // phase 2: out_edge[e][h] = sum_m gelu_ag[h][m] * w_e[m]
    if (t < 4 && t < cnt) { int e = csr[beg + t]; es[0][t] = e; ss[0][t] = src[e]; }
    __syncthreads();
    buf = 0;
    for (int i0 = 0; i0 < cnt; i0 += 4, buf ^= 1) {
        int nb = min(4, cnt - i0);
        if (t < nb * MIX) {
            int b = t >> 3, m = t & 7;
            ws[buf][b][m] = Wnode[ss[buf][b] * MIX + m];
        }
        // snapshot edge ids to registers BEFORE prefetch overwrites region
        int e0 = es[buf][0], e1 = es[buf][1], e2 = es[buf][2], e3 = es[buf][3];
        int i1 = i0 + 4;
        if (t < 4 && i1 + t < cnt) {
            int e = csr[beg + i1 + t];
            es[buf ^ 1][t] = e; ss[buf ^ 1][t] = src[e];
        }
        __syncthreads();
        int er[4] = {e0, e1, e2, e3};
#pragma unroll
        for (int b = 0; b < 4; ++b) {
            if (b >= nb) break;
            float4 w0 = *((const float4*)&ws[buf][b][0]);
            float4 w1 = *((const float4*)&ws[buf][b][4]);
            float p = ag[0] * w0.x + ag[1] * w0.y + ag[2] * w0.z + ag[3] * w0.w
                    + ag[4] * w1.x + ag[5] * w1.y + ag[6] * w1.z + ag[7] * w1.w;
            out_edge[(size_t)er[b] * HIDDEN + t] = p;
        }
    }
}

extern "C" void kernel_launch(void* const* d_in, const int* in_sizes, int n_in,
                              void* d_out, int out_size, void* d_ws, size_t ws_size,
                              hipStream_t stream) {
    const float* X   = (const float*)d_in[0];
    const float* W_A = (const float*)d_in[1];
    const float* W_B = (const float*)d_in[2];
    const int*   ei  = (const int*)d_in[3];

    const int N = in_sizes[0] / HIDDEN;
    const int E = in_sizes[3] / 2;
    const int* src = ei;
    const int* dst = ei + E;

    float* out      = (float*)d_out;
    float* out_edge = out;                        // (E, 128)
    float* out_src  = out + (size_t)E * HIDDEN;   // (E,)
    float* out_dst  = out_src + E;                // (E,)

    // workspace layout: [counts N][cursor N][offsets N+1][csr E][Wnode N*MIX]
    int* counts  = (int*)d_ws;
    int* cursor  = counts + N;
    int* offsets = cursor + N;
    int* csr     = offsets + (N + 1);
    float* Wnode = (float*)(csr + E);

    hipMemsetAsync(counts, 0, sizeof(int) * (size_t)(2 * N), stream);

    k_wnode<<<(N + NB - 1) / NB, 256, 0, stream>>>(X, W_A, W_B, Wnode, N);

    int eb = (E + 255) / 256;
    k_hist<<<eb, 256, 0, stream>>>(src, dst, counts, out_src, out_dst, E);
    k_scan<<<1, 1024, 0, stream>>>(counts, offsets, N);
    k_fill<<<eb, 256, 0, stream>>>(dst, cursor, offsets, csr, E);
    k_node<<<N, 128, 0, stream>>>(X, Wnode, src, csr, offsets, out_edge);
}

// Round 3
// 279.929 us; speedup vs baseline: 1.7698x; 1.0739x over previous
//
#include <hip/hip_runtime.h>
#include <hip/hip_bf16.h>

#define HIDDEN 128
#define MIX 8

// ---- k_wnode tiling params ----
#define NBW 32   // nodes per block
#define LDX 33   // xs row stride (odd -> 4*LDX%32=4 -> 8 distinct banks for n-groups)
#define KT  16   // k-slab width for W_A
#define LDW 17   // wa slab row stride (odd -> 4*LDW%32=4 -> 8 distinct banks for j-groups)
#define LDG 132  // gsm/wb row stride (132%32=4 -> distinct banks, float4-aligned)

__device__ __forceinline__ float gelu_exact(float x) {
    return 0.5f * x * (1.0f + erff(x * 0.7071067811865476f));
}

// K1: Wnode[n][m] = sum_k gelu(X[n]·W_A[k,:]) * W_B[m][k]
// 256 threads, 32 nodes/block. Register tile: 4 nodes x 4 j per thread.
__global__ __launch_bounds__(256) void k_wnode(const float* __restrict__ X,
                                               const float* __restrict__ W_A,
                                               const float* __restrict__ W_B,
                                               float* __restrict__ Wnode,
                                               int N) {
    __shared__ float xs[NBW * LDX];    // 4.2 KB: X rows (32 x 128)
    __shared__ float wa[HIDDEN * LDW]; // 8.7 KB: W_A k-slab (128 x 16)
    __shared__ float gsm[NBW * LDG];   // 16.9 KB: gelu(X@W_A^T) (32 x 128)
    __shared__ float wb[MIX * LDG];    // 4.2 KB: W_B (8 x 128)

    int t = threadIdx.x;
    int n0 = blockIdx.x * NBW;

    // stage X rows: r = t>>3 (0..31), cols (t&7)*16 .. +15
    {
        int r = t >> 3;
        int c0 = (t & 7) * 16;
        int rn = n0 + r; if (rn >= N) rn = N - 1;
        const float* xp = X + (size_t)rn * HIDDEN + c0;
        float4 a = ((const float4*)xp)[0];
        float4 b = ((const float4*)xp)[1];
        float4 c = ((const float4*)xp)[2];
        float4 d = ((const float4*)xp)[3];
        float tmp[16] = {a.x,a.y,a.z,a.w, b.x,b.y,b.z,b.w,
                         c.x,c.y,c.z,c.w, d.x,d.y,d.z,d.w};
#pragma unroll
        for (int q = 0; q < 16; ++q) xs[r * LDX + c0 + q] = tmp[q];
    }

    int ngrp = t & 7;    // 8 groups x 4 nodes
    int jgrp = t >> 3;   // 32 groups x 4 j
    float acc[4][4];
#pragma unroll
    for (int i = 0; i < 4; ++i)
#pragma unroll
        for (int j = 0; j < 4; ++j) acc[i][j] = 0.f;

    for (int kt = 0; kt < HIDDEN; kt += KT) {
        __syncthreads();  // protect wa (and xs on first iter)
        {   // stage W_A slab: j = t>>1 (0..127), cols kt + (t&1)*8 .. +7
            int j = t >> 1;
            int c0 = (t & 1) * 8;
            const float* wp = W_A + (size_t)j * HIDDEN + kt + c0;
            float4 a = ((const float4*)wp)[0];
            float4 b = ((const float4*)wp)[1];
            float tmp[8] = {a.x,a.y,a.z,a.w, b.x,b.y,b.z,b.w};
#pragma unroll
            for (int q = 0; q < 8; ++q) wa[j * LDW + c0 + q] = tmp[q];
        }
        __syncthreads();
#pragma unroll
        for (int k = 0; k < KT; ++k) {
            float xv[4], wv[4];
#pragma unroll
            for (int i = 0; i < 4; ++i) xv[i] = xs[(ngrp * 4 + i) * LDX + kt + k];
#pragma unroll
            for (int j = 0; j < 4; ++j) wv[j] = wa[(jgrp * 4 + j) * LDW + k];
#pragma unroll
            for (int i = 0; i < 4; ++i)
#pragma unroll
                for (int j = 0; j < 4; ++j) acc[i][j] += xv[i] * wv[j];
        }
    }

    // gelu -> gsm[n][j]
#pragma unroll
    for (int i = 0; i < 4; ++i)
#pragma unroll
        for (int j = 0; j < 4; ++j)
            gsm[(ngrp * 4 + i) * LDG + (jgrp * 4 + j)] = gelu_exact(acc[i][j]);

    // stage W_B (8 x 128): t<64: r=t>>3, cols (t&7)*16..+15
    if (t < 64) {
        int r = t >> 3;
        int c0 = (t & 7) * 16;
        const float* wp = W_B + (size_t)r * HIDDEN + c0;
        float4 a = ((const float4*)wp)[0];
        float4 b = ((const float4*)wp)[1];
        float4 c = ((const float4*)wp)[2];
        float4 d = ((const float4*)wp)[3];
        float tmp[16] = {a.x,a.y,a.z,a.w, b.x,b.y,b.z,b.w,
                         c.x,c.y,c.z,c.w, d.x,d.y,d.z,d.w};
#pragma unroll
        for (int q = 0; q < 16; ++q) wb[r * LDG + c0 + q] = tmp[q];
    }
    __syncthreads();

    // phase B: thread t -> n = t>>3, m = t&7
    {
        int n = t >> 3;
        int m = t & 7;
        float a = 0.f;
#pragma unroll 8
        for (int k = 0; k < HIDDEN; ++k)
            a += gsm[n * LDG + k] * wb[m * LDG + k];
        if (n0 + n < N) Wnode[(size_t)n0 * MIX + t] = a;  // n0*8 + n*8 + m == n0*8 + t
    }
}

// K2: histogram of dst + echo src/dst as float outputs.
__global__ __launch_bounds__(256) void k_hist(const int* __restrict__ src,
                                              const int* __restrict__ dst,
                                              int* __restrict__ counts,
                                              float* __restrict__ out_src,
                                              float* __restrict__ out_dst,
                                              int E) {
    int e = blockIdx.x * 256 + threadIdx.x;
    if (e < E) {
        int d = dst[e];
        atomicAdd(&counts[d], 1);
        out_src[e] = (float)src[e];
        out_dst[e] = (float)d;
    }
}

// K3: exclusive prefix sum over counts -> offsets (single block, 1024 threads).
__global__ __launch_bounds__(1024) void k_scan(const int* __restrict__ counts,
                                               int* __restrict__ offsets,
                                               int N) {
    __shared__ int ls[1024];
    int t = threadIdx.x;
    int chunk = (N + 1023) / 1024;
    int begin = t * chunk;
    int end = begin + chunk; if (end > N) end = N;
    int s = 0;
    for (int i = begin; i < end; ++i) s += counts[i];
    ls[t] = s;
    __syncthreads();
    for (int off = 1; off < 1024; off <<= 1) {
        int v = (t >= off) ? ls[t - off] : 0;
        __syncthreads();
        ls[t] += v;
        __syncthreads();
    }
    int run = (t == 0) ? 0 : ls[t - 1];
    for (int i = begin; i < end; ++i) { offsets[i] = run; run += counts[i]; }
    if (t == 1023) offsets[N] = run;  // == E
}

// K4: fill CSR edge lists.
__global__ __launch_bounds__(256) void k_fill(const int* __restrict__ dst,
                                              int* __restrict__ cursor,
                                              const int* __restrict__ offsets,
                                              int* __restrict__ csr,
                                              int E) {
    int e = blockIdx.x * 256 + threadIdx.x;
    if (e < E) {
        int d = dst[e];
        int p = atomicAdd(&cursor[d], 1);
        csr[offsets[d] + p] = e;
    }
}

// K5: wave-per-node. Lane owns h = 2*lane, 2*lane+1; 16 accumulators in VGPRs.
// Edge ids loaded once per 64-chunk (coalesced), broadcast via v_readlane.
// Wnode w-vectors via scalar loads (uniform address). No LDS, no barriers.
__global__ __launch_bounds__(256) void k_node(const float* __restrict__ X,
                                              const float* __restrict__ Wnode,
                                              const int* __restrict__ src,
                                              const int* __restrict__ csr,
                                              const int* __restrict__ offsets,
                                              float* __restrict__ out_edge,
                                              int N) {
    int lane = threadIdx.x & 63;
    int n = blockIdx.x * 4 + (threadIdx.x >> 6);
    if (n >= N) return;
    int beg = offsets[n];
    int cnt = offsets[n + 1] - beg;
    if (cnt == 0) return;

    float ag0[MIX], ag1[MIX];
#pragma unroll
    for (int m = 0; m < MIX; ++m) { ag0[m] = 0.f; ag1[m] = 0.f; }

    // ---- phase 1: aggregate ----
    for (int c0 = 0; c0 < cnt; c0 += 64) {
        int nb = min(64, cnt - c0);
        int idx = c0 + ((lane < nb) ? lane : 0);
        int e_l = csr[beg + idx];
        int s_l = src[e_l];
#pragma unroll 2
        for (int i = 0; i < nb; ++i) {
            int s = __builtin_amdgcn_readlane(s_l, i);
            const float* wp = Wnode + (size_t)s * MIX;
            float2 x = ((const float2*)(X + (size_t)s * HIDDEN))[lane];
#pragma unroll
            for (int m = 0; m < MIX; ++m) {
                float w = wp[m];
                ag0[m] += x.x * w;
                ag1[m] += x.y * w;
            }
        }
    }

#pragma unroll
    for (int m = 0; m < MIX; ++m) {
        ag0[m] = gelu_exact(ag0[m]);
        ag1[m] = gelu_exact(ag1[m]);
    }

    // ---- phase 2: per-edge output ----
    for (int c0 = 0; c0 < cnt; c0 += 64) {
        int nb = min(64, cnt - c0);
        int idx = c0 + ((lane < nb) ? lane : 0);
        int e_l = csr[beg + idx];
        int s_l = src[e_l];
#pragma unroll 2
        for (int i = 0; i < nb; ++i) {
            int s = __builtin_amdgcn_readlane(s_l, i);
            int e = __builtin_amdgcn_readlane(e_l, i);
            const float* wp = Wnode + (size_t)s * MIX;
            float2 o;
            o.x = ag0[0]*wp[0] + ag0[1]*wp[1] + ag0[2]*wp[2] + ag0[3]*wp[3]
                + ag0[4]*wp[4] + ag0[5]*wp[5] + ag0[6]*wp[6] + ag0[7]*wp[7];
            o.y = ag1[0]*wp[0] + ag1[1]*wp[1] + ag1[2]*wp[2] + ag1[3]*wp[3]
                + ag1[4]*wp[4] + ag1[5]*wp[5] + ag1[6]*wp[6] + ag1[7]*wp[7];
            ((float2*)(out_edge + (size_t)e * HIDDEN))[lane] = o;
        }
    }
}

extern "C" void kernel_launch(void* const* d_in, const int* in_sizes, int n_in,
                              void* d_out, int out_size, void* d_ws, size_t ws_size,
                              hipStream_t stream) {
    const float* X   = (const float*)d_in[0];
    const float* W_A = (const float*)d_in[1];
    const float* W_B = (const float*)d_in[2];
    const int*   ei  = (const int*)d_in[3];

    const int N = in_sizes[0] / HIDDEN;
    const int E = in_sizes[3] / 2;
    const int* src = ei;
    const int* dst = ei + E;

    float* out      = (float*)d_out;
    float* out_edge = out;                        // (E, 128)
    float* out_src  = out + (size_t)E * HIDDEN;   // (E,)
    float* out_dst  = out_src + E;                // (E,)

    // workspace: [counts N][cursor N][offsets N+1][csr E][Wnode N*MIX]
    int* counts  = (int*)d_ws;
    int* cursor  = counts + N;
    int* offsets = cursor + N;
    int* csr     = offsets + (N + 1);
    float* Wnode = (float*)(csr + E);

    hipMemsetAsync(counts, 0, sizeof(int) * (size_t)(2 * N), stream);

    k_wnode<<<(N + NBW - 1) / NBW, 256, 0, stream>>>(X, W_A, W_B, Wnode, N);

    int eb = (E + 255) / 256;
    k_hist<<<eb, 256, 0, stream>>>(src, dst, counts, out_src, out_dst, E);
    k_scan<<<1, 1024, 0, stream>>>(counts, offsets, N);
    k_fill<<<eb, 256, 0, stream>>>(dst, cursor, offsets, csr, E);
    k_node<<<(N + 3) / 4, 256, 0, stream>>>(X, Wnode, src, csr, offsets, out_edge, N);
}